// Round 2
// baseline (3367.517 us; speedup 1.0000x reference)
//
#include <hip/hip_runtime.h>
#include <math.h>

#define NPTS  10000
#define KNB   32
#define NCELL 216     // 6*6*6
#define NSGT  157     // ceil(NPTS/64) sort groups
#define NPAIR 79      // ceil(NSGT/2) pair blocks

// ---------------------------------------------------------------------------
// helpers
// ---------------------------------------------------------------------------
__device__ __forceinline__ float sgnf(float v) {
    return (v > 0.0f) ? 1.0f : ((v < 0.0f) ? -1.0f : 0.0f);
}

// Open3D ball->cube volume-preserving map, transcribed from the reference.
__device__ __forceinline__ void ball_to_cube(float x, float y, float z,
                                             float& X, float& Y, float& Z) {
    const float EPSF = 1e-12f;
    const float FOPI = (float)(4.0 / 3.14159265358979323846);
    float sq   = x * x + y * y + z * z;
    float norm = sqrtf(fmaxf(sq, EPSF));
    float rho2 = x * x + y * y;
    bool in_cone = (1.25f * z * z > rho2);
    float s1 = sqrtf(3.0f * norm / (norm + fabsf(z)));
    float s2 = norm / sqrtf(fmaxf(rho2, EPSF));
    float s  = in_cone ? s1 : s2;
    float xc = x * s;
    float yc = y * s;
    float zc = in_cone ? sgnf(z) * norm : 1.5f * z;
    if (sq < EPSF) { xc = 0.0f; yc = 0.0f; zc = 0.0f; }
    float sq_xy   = xc * xc + yc * yc;
    float norm_xy = sqrtf(fmaxf(sq_xy, EPSF));
    bool x_major = (fabsf(yc) <= fabsf(xc));
    float xd = (fabsf(xc) < EPSF) ? 1.0f : xc;
    float yd = (fabsf(yc) < EPSF) ? 1.0f : yc;
    float tx = sgnf(xc) * norm_xy;
    float ty = sgnf(yc) * norm_xy;
    float xq = x_major ? tx : ty * FOPI * atanf(xc / yd);
    float yq = x_major ? tx * FOPI * atanf(yc / xd) : ty;
    if (sq_xy < EPSF) { xq = 0.0f; yq = 0.0f; }
    X = xq; Y = yq; Z = zc;
}

// ---------------------------------------------------------------------------
// Kernel 1: per-(point,neighbor) geometry record + neighbor counts.
// Record (uint4): x,y,z = trilinear fracs (fp32 bits); w = packed:
//   [7:0]=c000 cell, [8]=dx?, [9]=dy?, [10]=dz?, [11]=valid, [25:12]=nidx
// ---------------------------------------------------------------------------
__global__ __launch_bounds__(256) void geom_kernel(
    const float* __restrict__ pos, const int* __restrict__ nidx,
    uint4* __restrict__ geo, float* __restrict__ cnt) {
    int t = blockIdx.x * 256 + threadIdx.x;
    if (t >= NPTS * KNB) return;
    int j = t >> 5;
    int k = t & 31;
    int nid = nidx[t];
    float px = pos[j * 3], py = pos[j * 3 + 1], pz = pos[j * 3 + 2];
    float qx = pos[nid * 3], qy = pos[nid * 3 + 1], qz = pos[nid * 3 + 2];
    // exact fp32 (no FMA contraction) to reproduce numpy's mask bit-for-bit
    float dx = __fsub_rn(px, qx), dy = __fsub_rn(py, qy), dz = __fsub_rn(pz, qz);
    float d2 = __fadd_rn(__fadd_rn(__fmul_rn(dx, dx), __fmul_rn(dy, dy)),
                         __fmul_rn(dz, dz));
    bool valid = (d2 <= 2.25f);
    if (valid && nid == 0) {
        for (int kk = 0; kk < k; ++kk) {
            if (nidx[j * KNB + kk] == 0) { valid = false; break; }
        }
    }
    uint4 g = make_uint4(0u, 0u, 0u, 0u);
    if (valid) {
        const float C = (float)(2.0 / 3.0);   // 2/EXTENT
        float ux = (qx - px) * C, uy = (qy - py) * C, uz = (qz - pz) * C;
        float X, Y, Z;
        ball_to_cube(ux, uy, uz, X, Y, Z);
        float cs[3] = { (X + 1.0f) * 2.5f, (Y + 1.0f) * 2.5f, (Z + 1.0f) * 2.5f };
        int i0[3], i1[3];
        float fr[3];
        #pragma unroll
        for (int d = 0; d < 3; ++d) {
            float f0 = floorf(cs[d]);
            fr[d] = cs[d] - f0;               // frac from UNCLIPPED floor (ref)
            int a = (int)f0;
            a = min(max(a, 0), 5);
            i0[d] = a;
            i1[d] = min(a + 1, 5);
        }
        int c000 = (i0[0] * 6 + i0[1]) * 6 + i0[2];
        unsigned bits = (unsigned)c000
                      | ((unsigned)(i1[0] - i0[0]) << 8)
                      | ((unsigned)(i1[1] - i0[1]) << 9)
                      | ((unsigned)(i1[2] - i0[2]) << 10)
                      | (1u << 11)
                      | ((unsigned)nid << 12);
        g.x = __float_as_uint(fr[0]);
        g.y = __float_as_uint(fr[1]);
        g.z = __float_as_uint(fr[2]);
        g.w = bits;
        atomicAdd(&cnt[j], 1.0f);
    }
    geo[t] = g;
}

// ---------------------------------------------------------------------------
// Kernel 2: counting sort of corner contributions by CELL per 64-pt sort
// group. Payload packs nid | ptl<<14 | cell<<20. starts[sg][217] = per-cell
// prefix. Built once, consumed by all 3 conv layers.
// ---------------------------------------------------------------------------
__global__ __launch_bounds__(256) void sort_kernel(
    const uint4* __restrict__ geo, uint2* __restrict__ contribs,
    int* __restrict__ starts) {
    __shared__ int hist[NCELL];
    __shared__ int pref[NCELL + 1];
    const int sg = blockIdx.x, tid = threadIdx.x;
    if (tid < NCELL) hist[tid] = 0;
    __syncthreads();
    const int npts = min(64, NPTS - sg * 64);
    const int nrec = npts * KNB;
    const uint4* gb = geo + (size_t)sg * 64 * KNB;
    for (int r = tid; r < nrec; r += 256) {
        uint4 g = gb[r];
        if (g.w & 2048u) {
            int c000 = g.w & 255u;
            int dxo = (g.w & 256u)  ? 36 : 0;
            int dyo = (g.w & 512u)  ? 6  : 0;
            int dzo = (g.w & 1024u) ? 1  : 0;
            #pragma unroll
            for (int c = 0; c < 8; ++c) {
                int cell = c000 + ((c & 4) ? dxo : 0) + ((c & 2) ? dyo : 0)
                                + ((c & 1) ? dzo : 0);
                atomicAdd(&hist[cell], 1);
            }
        }
    }
    __syncthreads();
    if (tid == 0) {
        int run = 0;
        for (int m = 0; m < NCELL; ++m) { pref[m] = run; run += hist[m]; }
        pref[NCELL] = run;
    }
    __syncthreads();
    for (int i = tid; i < NCELL + 1; i += 256)
        starts[sg * (NCELL + 1) + i] = pref[i];
    if (tid < NCELL) hist[tid] = pref[tid];   // cursors
    __syncthreads();
    uint2* cb = contribs + (size_t)sg * 16384;
    for (int r = tid; r < nrec; r += 256) {
        uint4 g = gb[r];
        if (g.w & 2048u) {
            int ptl = r >> 5;
            float fx = __uint_as_float(g.x);
            float fy = __uint_as_float(g.y);
            float fz = __uint_as_float(g.z);
            int c000 = g.w & 255u;
            int dxo = (g.w & 256u)  ? 36 : 0;
            int dyo = (g.w & 512u)  ? 6  : 0;
            int dzo = (g.w & 1024u) ? 1  : 0;
            int nid = (g.w >> 12) & 16383u;
            #pragma unroll
            for (int c = 0; c < 8; ++c) {
                float wgt = ((c & 4) ? fx : 1.f - fx)
                          * ((c & 2) ? fy : 1.f - fy)
                          * ((c & 1) ? fz : 1.f - fz);
                int cell = c000 + ((c & 4) ? dxo : 0) + ((c & 2) ? dyo : 0)
                                + ((c & 1) ? dzo : 0);
                int p = atomicAdd(&hist[cell], 1);
                cb[p] = make_uint2(__float_as_uint(wgt),
                                   (unsigned)nid | ((unsigned)ptl << 14)
                                                 | ((unsigned)cell << 20));
            }
        }
    }
}

// ---------------------------------------------------------------------------
// Kernel 3: conv as A-in-LDS / W-wave-uniform GEMM with point-direction
// register blocking.
//   NSG sort groups per block (NROW = NSG*64 points); 8 waves; wave w owns
//   C = COUT/COSPLIT/8 couts (wave-uniform W address); lane = pt%64, each
//   thread accumulates NSG points x C couts -> every W float4 load feeds
//   4*NSG FMAs (was 4). COSPLIT splits couts across blocks to keep the grid
//   full without extra partial-buffer space.
// A-tile (NROW x KC, stride KC+4 -> conflict-free b128) double-buffered in
// LDS; scatter of chunk c+1 overlaps GEMM of chunk c. K-split over
// blockIdx.y into partial buffers.
// ---------------------------------------------------------------------------
template<int CIN, int COUT, int CPC, int KSPLIT, int NSG, int COSPLIT>
__global__ __launch_bounds__(512, 4) void conv_kernel(
    const float* __restrict__ feats, const float* __restrict__ W,
    const uint2* __restrict__ contribs, const int* __restrict__ starts,
    float* __restrict__ partial) {
    constexpr int KC   = CPC * CIN;        // K per chunk
    constexpr int ASTR = KC + 4;           // quad-stride 1 mod 8: b128-clean
    constexpr int BT   = 512;              // threads (8 waves)
    constexpr int NROW = NSG * 64;         // points per block
    constexpr int NCHUNK = NCELL / CPC;
    constexpr int TPC  = CIN / 4;          // threads per contribution
    constexpr int GPB  = BT / TPC;         // contributions in flight
    constexpr int C    = COUT / COSPLIT / 8; // couts per wave

    __shared__ alignas(16) float Ab[2][NROW * ASTR];

    const int tid   = threadIdx.x;
    const int lane  = tid & 63;
    const int wvid  = __builtin_amdgcn_readfirstlane(tid >> 6);
    const int bx    = blockIdx.x;          // sort-group (pair) index
    const int ks    = blockIdx.y % KSPLIT;
    const int coh   = blockIdx.y / KSPLIT; // cout-half
    const int cow   = coh * (COUT / COSPLIT) + wvid * C;  // wave-uniform
    const int gslot = tid / TPC;
    const int ch    = tid % TPC;

    const int c0 = NCHUNK * ks / KSPLIT;
    const int c1 = NCHUNK * (ks + 1) / KSPLIT;

    auto zero = [&](int b) {
        float4 z; z.x = z.y = z.z = z.w = 0.f;
        float4* p = reinterpret_cast<float4*>(Ab[b]);
        #pragma unroll 2
        for (int i = tid; i < NROW * ASTR / 4; i += BT) p[i] = z;
    };
    auto scatter = [&](int c, int b) {
        #pragma unroll
        for (int grp = 0; grp < NSG; ++grp) {
            const int sg = bx * NSG + grp;
            if (NSG > 1 && sg >= NSGT) continue;
            const uint2* cbs = contribs + (size_t)sg * 16384;
            const int*   st  = starts + sg * (NCELL + 1);
            const int s = st[c * CPC], e = st[c * CPC + CPC];
            const int cb4 = c * CPC;
            for (int i = s + gslot; i < e; i += GPB) {
                uint2 rec = cbs[i];
                float wgt = __uint_as_float(rec.x);
                int nid = rec.y & 16383;
                int ptl = (rec.y >> 14) & 63;
                int cel = (int)(rec.y >> 20);
                float4 f4 = *reinterpret_cast<const float4*>(
                    feats + (size_t)nid * CIN + ch * 4);
                float* dst = &Ab[b][(grp * 64 + ptl) * ASTR
                                    + (cel - cb4) * CIN + ch * 4];
                atomicAdd(dst + 0, wgt * f4.x);
                atomicAdd(dst + 1, wgt * f4.y);
                atomicAdd(dst + 2, wgt * f4.z);
                atomicAdd(dst + 3, wgt * f4.w);
            }
        }
    };

    zero(0); zero(1);
    __syncthreads();
    scatter(c0, 0);
    __syncthreads();

    float acc[NSG][C];
    #pragma unroll
    for (int p = 0; p < NSG; ++p)
        #pragma unroll
        for (int j = 0; j < C; ++j) acc[p][j] = 0.f;

    for (int c = c0; c < c1; ++c) {
        const int b = (c - c0) & 1;
        if (c + 1 < c1) scatter(c + 1, b ^ 1);   // overlaps GEMM below
        const float* Wc = W + (size_t)c * CPC * CIN * COUT;  // k-major
        #pragma unroll 4
        for (int g = 0; g < KC / 4; ++g) {
            float av[NSG][4];
            #pragma unroll
            for (int p = 0; p < NSG; ++p) {
                float4 a4 = *reinterpret_cast<const float4*>(
                    Ab[b] + (p * 64 + lane) * ASTR + g * 4);
                av[p][0] = a4.x; av[p][1] = a4.y;
                av[p][2] = a4.z; av[p][3] = a4.w;
            }
            #pragma unroll
            for (int j = 0; j < 4; ++j) {
                #pragma unroll
                for (int cc = 0; cc < C / 4; ++cc) {
                    float4 w4 = *reinterpret_cast<const float4*>(
                        Wc + (size_t)(g * 4 + j) * COUT + cow + cc * 4);
                    #pragma unroll
                    for (int p = 0; p < NSG; ++p) {
                        float a = av[p][j];
                        acc[p][cc * 4 + 0] = fmaf(a, w4.x, acc[p][cc * 4 + 0]);
                        acc[p][cc * 4 + 1] = fmaf(a, w4.y, acc[p][cc * 4 + 1]);
                        acc[p][cc * 4 + 2] = fmaf(a, w4.z, acc[p][cc * 4 + 2]);
                        acc[p][cc * 4 + 3] = fmaf(a, w4.w, acc[p][cc * 4 + 3]);
                    }
                }
            }
        }
        __syncthreads();
        zero(b);          // recycle buf b for chunk c+2
        __syncthreads();
    }

    #pragma unroll
    for (int p = 0; p < NSG; ++p) {
        const int n = bx * NROW + p * 64 + lane;
        if (n < NPTS) {
            float* po = partial + ((size_t)ks * NPTS + n) * COUT + cow;
            #pragma unroll
            for (int cc = 0; cc < C / 4; ++cc)
                *reinterpret_cast<float4*>(po + cc * 4) =
                    make_float4(acc[p][cc * 4 + 0], acc[p][cc * 4 + 1],
                                acc[p][cc * 4 + 2], acc[p][cc * 4 + 3]);
        }
    }
}

// ---------------------------------------------------------------------------
// Kernel 4: combine K-split partials, normalize by neighbor count, bias, relu.
// ---------------------------------------------------------------------------
template<int COUT, int KSPLIT>
__global__ __launch_bounds__(256) void combine_kernel(
    const float* __restrict__ partial, const float* __restrict__ cnt,
    const float* __restrict__ bias, float* __restrict__ out) {
    int idx = blockIdx.x * 256 + threadIdx.x;
    if (idx >= NPTS * COUT) return;
    int n = idx / COUT, co = idx % COUT;
    float s = 0.f;
    #pragma unroll
    for (int k2 = 0; k2 < KSPLIT; ++k2)
        s += partial[((size_t)k2 * NPTS + n) * COUT + co];
    float c = cnt[n];
    if (c > 0.f) s /= fmaxf(c, 1.f);
    out[idx] = fmaxf(s + bias[co], 0.f);
}

// ---------------------------------------------------------------------------
// Kernel 5: fused FC chain. One wave per point, __shfl broadcasts.
// ---------------------------------------------------------------------------
__global__ __launch_bounds__(64) void fc_kernel(
    const float* __restrict__ x,
    const float* __restrict__ W1, const float* __restrict__ b1,
    const float* __restrict__ W2, const float* __restrict__ b2,
    const float* __restrict__ W3, const float* __restrict__ b3,
    const float* __restrict__ W4, const float* __restrict__ b4,
    float* __restrict__ out) {
    int n = blockIdx.x;
    int lane = threadIdx.x;
    float xv = (lane < 32) ? x[(size_t)n * 32 + lane] : 0.0f;

    float t = b1[lane];
    for (int ci = 0; ci < 32; ++ci)
        t = fmaf(__shfl(xv, ci), W1[ci * 64 + lane], t);
    float h1 = fmaxf(t, 0.0f);

    t = b2[lane];
    for (int ci = 0; ci < 64; ++ci)
        t = fmaf(__shfl(h1, ci), W2[ci * 64 + lane], t);
    float h2 = fmaxf(t, 0.0f);

    int l32 = lane & 31;
    t = b3[l32];
    for (int ci = 0; ci < 64; ++ci)
        t = fmaf(__shfl(h2, ci), W3[ci * 32 + l32], t);
    float h3 = fmaxf(t, 0.0f);

    int ch = (lane < 3) ? lane : 0;
    float o = b4[ch];
    for (int ci = 0; ci < 32; ++ci)
        o = fmaf(__shfl(h3, ci), W4[ci * 3 + ch], o);
    if (lane < 3) out[(size_t)n * 3 + lane] = o;
}

// ---------------------------------------------------------------------------
// launch
// ---------------------------------------------------------------------------
extern "C" void kernel_launch(void* const* d_in, const int* in_sizes, int n_in,
                              void* d_out, int out_size, void* d_ws, size_t ws_size,
                              hipStream_t stream) {
    const float* feats = (const float*)d_in[0];
    const float* pos   = (const float*)d_in[1];
    const int*   nidx  = (const int*)d_in[2];
    // d_in[3] (neighbor_mask) unused: mask recomputed exactly.
    const float* W1 = (const float*)d_in[4];
    const float* b1 = (const float*)d_in[5];
    const float* W2 = (const float*)d_in[6];
    const float* b2 = (const float*)d_in[7];
    const float* W3 = (const float*)d_in[8];
    const float* b3 = (const float*)d_in[9];
    const float* Wfc1 = (const float*)d_in[10];
    const float* bfc1 = (const float*)d_in[11];
    const float* Wfc2 = (const float*)d_in[12];
    const float* bfc2 = (const float*)d_in[13];
    const float* Wfc3 = (const float*)d_in[14];
    const float* bfc3 = (const float*)d_in[15];
    const float* Wout = (const float*)d_in[16];
    const float* bout = (const float*)d_in[17];

    char* ws = (char*)d_ws;
    uint2* contrib = (uint2*)(ws);                    // 20,578,304 B
    int*   starts  = (int*)  (ws + 20578304);         //    136,276 B
    float* cnt     = (float*)(ws + 20714624);         //     40,000 B
    float* x1      = (float*)(ws + 20754624);         //  2,560,000 B
    float* x2      = (float*)(ws + 23314624);         //  2,560,000 B
    float* x3      = (float*)(ws + 25874624);         //  1,280,000 B
    // geo (5.12 MB) dead after sort -> alias with partial region (10.24 MB max)
    uint4* geo     = (uint4*)(ws + 27154624);
    float* partial = (float*)(ws + 27154624);

    hipMemsetAsync(cnt, 0, NPTS * sizeof(float), stream);
    geom_kernel<<<(NPTS * KNB) / 256, 256, 0, stream>>>(pos, nidx, geo, cnt);
    sort_kernel<<<NSGT, 256, 0, stream>>>(geo, contrib, starts);

    // conv1: CIN=4, COUT=64, CPC=8 (KC=32), NSG=1, KSPLIT=4 (unchanged config)
    conv_kernel<4, 64, 8, 4, 1, 1><<<dim3(NSGT, 4), 512, 0, stream>>>(
        feats, W1, contrib, starts, partial);
    combine_kernel<64, 4><<<(NPTS * 64 + 255) / 256, 256, 0, stream>>>(
        partial, cnt, b1, x1);

    // conv2: CIN=64, COUT=64, CPC=1 (KC=64), NSG=2 (128 pts/block),
    // KSPLIT=4 x COSPLIT=2 -> grid 79x8 = 632 blocks, partial 10.24 MB
    conv_kernel<64, 64, 1, 4, 2, 2><<<dim3(NPAIR, 8), 512, 0, stream>>>(
        x1, W2, contrib, starts, partial);
    combine_kernel<64, 4><<<(NPTS * 64 + 255) / 256, 256, 0, stream>>>(
        partial, cnt, b2, x2);

    // conv3: CIN=64, COUT=32, CPC=1, NSG=2, KSPLIT=8 -> grid 79x8,
    // partial 10.24 MB
    conv_kernel<64, 32, 1, 8, 2, 1><<<dim3(NPAIR, 8), 512, 0, stream>>>(
        x2, W3, contrib, starts, partial);
    combine_kernel<32, 8><<<(NPTS * 32 + 255) / 256, 256, 0, stream>>>(
        partial, cnt, b3, x3);

    fc_kernel<<<NPTS, 64, 0, stream>>>(x3, Wfc1, bfc1, Wfc2, bfc2,
                                       Wfc3, bfc3, Wout, bout, (float*)d_out);
}

// Round 3
// 2324.742 us; speedup vs baseline: 1.4486x; 1.4486x over previous
//
#include <hip/hip_runtime.h>
#include <math.h>

#define NPTS  10000
#define KNB   32
#define NCELL 216     // 6*6*6
#define NSGT  157     // ceil(NPTS/64) sort groups

// ---------------------------------------------------------------------------
// helpers
// ---------------------------------------------------------------------------
__device__ __forceinline__ float sgnf(float v) {
    return (v > 0.0f) ? 1.0f : ((v < 0.0f) ? -1.0f : 0.0f);
}

// Open3D ball->cube volume-preserving map, transcribed from the reference.
__device__ __forceinline__ void ball_to_cube(float x, float y, float z,
                                             float& X, float& Y, float& Z) {
    const float EPSF = 1e-12f;
    const float FOPI = (float)(4.0 / 3.14159265358979323846);
    float sq   = x * x + y * y + z * z;
    float norm = sqrtf(fmaxf(sq, EPSF));
    float rho2 = x * x + y * y;
    bool in_cone = (1.25f * z * z > rho2);
    float s1 = sqrtf(3.0f * norm / (norm + fabsf(z)));
    float s2 = norm / sqrtf(fmaxf(rho2, EPSF));
    float s  = in_cone ? s1 : s2;
    float xc = x * s;
    float yc = y * s;
    float zc = in_cone ? sgnf(z) * norm : 1.5f * z;
    if (sq < EPSF) { xc = 0.0f; yc = 0.0f; zc = 0.0f; }
    float sq_xy   = xc * xc + yc * yc;
    float norm_xy = sqrtf(fmaxf(sq_xy, EPSF));
    bool x_major = (fabsf(yc) <= fabsf(xc));
    float xd = (fabsf(xc) < EPSF) ? 1.0f : xc;
    float yd = (fabsf(yc) < EPSF) ? 1.0f : yc;
    float tx = sgnf(xc) * norm_xy;
    float ty = sgnf(yc) * norm_xy;
    float xq = x_major ? tx : ty * FOPI * atanf(xc / yd);
    float yq = x_major ? tx * FOPI * atanf(yc / xd) : ty;
    if (sq_xy < EPSF) { xq = 0.0f; yq = 0.0f; }
    X = xq; Y = yq; Z = zc;
}

// ---------------------------------------------------------------------------
// Kernel 1: per-(point,neighbor) geometry record + neighbor counts.
// Record (uint4): x,y,z = trilinear fracs (fp32 bits); w = packed:
//   [7:0]=c000 cell, [8]=dx?, [9]=dy?, [10]=dz?, [11]=valid, [25:12]=nidx
// ---------------------------------------------------------------------------
__global__ __launch_bounds__(256) void geom_kernel(
    const float* __restrict__ pos, const int* __restrict__ nidx,
    uint4* __restrict__ geo, float* __restrict__ cnt) {
    int t = blockIdx.x * 256 + threadIdx.x;
    if (t >= NPTS * KNB) return;
    int j = t >> 5;
    int k = t & 31;
    int nid = nidx[t];
    float px = pos[j * 3], py = pos[j * 3 + 1], pz = pos[j * 3 + 2];
    float qx = pos[nid * 3], qy = pos[nid * 3 + 1], qz = pos[nid * 3 + 2];
    // exact fp32 (no FMA contraction) to reproduce numpy's mask bit-for-bit
    float dx = __fsub_rn(px, qx), dy = __fsub_rn(py, qy), dz = __fsub_rn(pz, qz);
    float d2 = __fadd_rn(__fadd_rn(__fmul_rn(dx, dx), __fmul_rn(dy, dy)),
                         __fmul_rn(dz, dz));
    bool valid = (d2 <= 2.25f);
    if (valid && nid == 0) {
        for (int kk = 0; kk < k; ++kk) {
            if (nidx[j * KNB + kk] == 0) { valid = false; break; }
        }
    }
    uint4 g = make_uint4(0u, 0u, 0u, 0u);
    if (valid) {
        const float C = (float)(2.0 / 3.0);   // 2/EXTENT
        float ux = (qx - px) * C, uy = (qy - py) * C, uz = (qz - pz) * C;
        float X, Y, Z;
        ball_to_cube(ux, uy, uz, X, Y, Z);
        float cs[3] = { (X + 1.0f) * 2.5f, (Y + 1.0f) * 2.5f, (Z + 1.0f) * 2.5f };
        int i0[3], i1[3];
        float fr[3];
        #pragma unroll
        for (int d = 0; d < 3; ++d) {
            float f0 = floorf(cs[d]);
            fr[d] = cs[d] - f0;               // frac from UNCLIPPED floor (ref)
            int a = (int)f0;
            a = min(max(a, 0), 5);
            i0[d] = a;
            i1[d] = min(a + 1, 5);
        }
        int c000 = (i0[0] * 6 + i0[1]) * 6 + i0[2];
        unsigned bits = (unsigned)c000
                      | ((unsigned)(i1[0] - i0[0]) << 8)
                      | ((unsigned)(i1[1] - i0[1]) << 9)
                      | ((unsigned)(i1[2] - i0[2]) << 10)
                      | (1u << 11)
                      | ((unsigned)nid << 12);
        g.x = __float_as_uint(fr[0]);
        g.y = __float_as_uint(fr[1]);
        g.z = __float_as_uint(fr[2]);
        g.w = bits;
        atomicAdd(&cnt[j], 1.0f);
    }
    geo[t] = g;
}

// ---------------------------------------------------------------------------
// Kernel 2: counting sort of corner contributions by CELL per 64-pt sort
// group. Payload packs nid | ptl<<14 | cell<<20. starts[sg][217] = per-cell
// prefix. Built once, consumed by all 3 conv layers.
// ---------------------------------------------------------------------------
__global__ __launch_bounds__(256) void sort_kernel(
    const uint4* __restrict__ geo, uint2* __restrict__ contribs,
    int* __restrict__ starts) {
    __shared__ int hist[NCELL];
    __shared__ int pref[NCELL + 1];
    const int sg = blockIdx.x, tid = threadIdx.x;
    if (tid < NCELL) hist[tid] = 0;
    __syncthreads();
    const int npts = min(64, NPTS - sg * 64);
    const int nrec = npts * KNB;
    const uint4* gb = geo + (size_t)sg * 64 * KNB;
    for (int r = tid; r < nrec; r += 256) {
        uint4 g = gb[r];
        if (g.w & 2048u) {
            int c000 = g.w & 255u;
            int dxo = (g.w & 256u)  ? 36 : 0;
            int dyo = (g.w & 512u)  ? 6  : 0;
            int dzo = (g.w & 1024u) ? 1  : 0;
            #pragma unroll
            for (int c = 0; c < 8; ++c) {
                int cell = c000 + ((c & 4) ? dxo : 0) + ((c & 2) ? dyo : 0)
                                + ((c & 1) ? dzo : 0);
                atomicAdd(&hist[cell], 1);
            }
        }
    }
    __syncthreads();
    if (tid == 0) {
        int run = 0;
        for (int m = 0; m < NCELL; ++m) { pref[m] = run; run += hist[m]; }
        pref[NCELL] = run;
    }
    __syncthreads();
    for (int i = tid; i < NCELL + 1; i += 256)
        starts[sg * (NCELL + 1) + i] = pref[i];
    if (tid < NCELL) hist[tid] = pref[tid];   // cursors
    __syncthreads();
    uint2* cb = contribs + (size_t)sg * 16384;
    for (int r = tid; r < nrec; r += 256) {
        uint4 g = gb[r];
        if (g.w & 2048u) {
            int ptl = r >> 5;
            float fx = __uint_as_float(g.x);
            float fy = __uint_as_float(g.y);
            float fz = __uint_as_float(g.z);
            int c000 = g.w & 255u;
            int dxo = (g.w & 256u)  ? 36 : 0;
            int dyo = (g.w & 512u)  ? 6  : 0;
            int dzo = (g.w & 1024u) ? 1  : 0;
            int nid = (g.w >> 12) & 16383u;
            #pragma unroll
            for (int c = 0; c < 8; ++c) {
                float wgt = ((c & 4) ? fx : 1.f - fx)
                          * ((c & 2) ? fy : 1.f - fy)
                          * ((c & 1) ? fz : 1.f - fz);
                int cell = c000 + ((c & 4) ? dxo : 0) + ((c & 2) ? dyo : 0)
                                + ((c & 1) ? dzo : 0);
                int p = atomicAdd(&hist[cell], 1);
                cb[p] = make_uint2(__float_as_uint(wgt),
                                   (unsigned)nid | ((unsigned)ptl << 14)
                                                 | ((unsigned)cell << 20));
            }
        }
    }
}

// ---------------------------------------------------------------------------
// Kernel 3: conv as A-in-LDS / W-wave-uniform GEMM (round-0 structure:
// 64 pts/block, 8 waves, C=COUT/8 couts per wave, lane = pt).
// Scatter improvements:
//   - record loads deduplicated: only the ch==0 lane of each TPC-lane group
//     loads cbs[i]; broadcast via __shfl (group-uniform trip count).
//   - 2-deep software pipeline: iteration t+1's record+feats loads issue
//     before iteration t's LDS atomics, hiding feats latency.
// Occupancy: KSPLIT=8 for all layers -> 1256 blocks (~4 resident/CU at
// 34.8KB LDS). Partial region stays <=10.24MB: when KSPLIT > PSLOT, two
// k-segments share a partial slot via global atomicAdd (partial pre-zeroed).
// ---------------------------------------------------------------------------
template<int CIN, int COUT, int CPC, int KSPLIT, int PSLOT>
__global__ __launch_bounds__(512, 8) void conv_kernel(
    const float* __restrict__ feats, const float* __restrict__ W,
    const uint2* __restrict__ contribs, const int* __restrict__ starts,
    float* __restrict__ partial) {
    constexpr int KC   = CPC * CIN;        // K per chunk
    constexpr int ASTR = KC + 4;           // quad-stride 1 mod 8: b128-clean
    constexpr int BT   = 512;              // threads (8 waves)
    constexpr int NCHUNK = NCELL / CPC;
    constexpr int TPC  = CIN / 4;          // threads per contribution
    constexpr int GPB  = BT / TPC;         // contributions in flight
    constexpr int C    = COUT / 8;         // couts per wave

    __shared__ alignas(16) float Ab[2][64 * ASTR];

    const int tid   = threadIdx.x;
    const int lane  = tid & 63;
    const int wvid  = __builtin_amdgcn_readfirstlane(tid >> 6);
    const int cow   = wvid * C;            // wave-uniform co base
    const int bx    = blockIdx.x;          // sort group
    const int ks    = blockIdx.y;
    const int gslot = tid / TPC;
    const int ch    = tid % TPC;

    const uint2* cbs = contribs + (size_t)bx * 16384;
    const int*   st  = starts + bx * (NCELL + 1);

    const int c0 = NCHUNK * ks / KSPLIT;
    const int c1 = NCHUNK * (ks + 1) / KSPLIT;

    auto zero = [&](int b) {
        float4 z; z.x = z.y = z.z = z.w = 0.f;
        float4* p = reinterpret_cast<float4*>(Ab[b]);
        #pragma unroll 2
        for (int i = tid; i < 64 * ASTR / 4; i += BT) p[i] = z;
    };
    // record load: ch==0 lane loads, broadcast across the TPC-lane group
    auto ldrec = [&](int i) -> uint2 {
        if constexpr (TPC > 1) {
            unsigned lo = 0u, hi = 0u;
            if (ch == 0) { uint2 r = cbs[i]; lo = r.x; hi = r.y; }
            int src = lane & ~(TPC - 1);
            lo = (unsigned)__shfl((int)lo, src);
            hi = (unsigned)__shfl((int)hi, src);
            return make_uint2(lo, hi);
        } else {
            return cbs[i];
        }
    };
    auto scatter = [&](int c, int b) {
        const int s = st[c * CPC], e = st[c * CPC + CPC];
        const int cb4 = c * CPC;
        int i = s + gslot;
        uint2 rec; float4 f4;
        if (i < e) {
            rec = ldrec(i);
            f4 = *reinterpret_cast<const float4*>(
                feats + (size_t)(rec.y & 16383u) * CIN + ch * 4);
        }
        while (i < e) {
            const int in = i + GPB;
            uint2 rec2; float4 f42;
            if (in < e) {
                rec2 = ldrec(in);
                f42 = *reinterpret_cast<const float4*>(
                    feats + (size_t)(rec2.y & 16383u) * CIN + ch * 4);
            }
            float wgt = __uint_as_float(rec.x);
            int ptl = (rec.y >> 14) & 63;
            int cel = (int)(rec.y >> 20);
            float* dst = &Ab[b][ptl * ASTR + (cel - cb4) * CIN + ch * 4];
            atomicAdd(dst + 0, wgt * f4.x);
            atomicAdd(dst + 1, wgt * f4.y);
            atomicAdd(dst + 2, wgt * f4.z);
            atomicAdd(dst + 3, wgt * f4.w);
            rec = rec2; f4 = f42; i = in;
        }
    };

    zero(0); zero(1);
    __syncthreads();
    scatter(c0, 0);
    __syncthreads();

    float acc[C];
    #pragma unroll
    for (int j = 0; j < C; ++j) acc[j] = 0.f;

    for (int c = c0; c < c1; ++c) {
        const int b = (c - c0) & 1;
        if (c + 1 < c1) scatter(c + 1, b ^ 1);   // overlaps GEMM below
        const float* Wc = W + (size_t)c * CPC * CIN * COUT;  // k-major
        const float* Ar = Ab[b] + lane * ASTR;
        #pragma unroll 4
        for (int g = 0; g < KC / 4; ++g) {
            float4 a4 = *reinterpret_cast<const float4*>(Ar + g * 4);
            const float av[4] = { a4.x, a4.y, a4.z, a4.w };
            #pragma unroll
            for (int j = 0; j < 4; ++j) {
                #pragma unroll
                for (int cc = 0; cc < C / 4; ++cc) {
                    float4 w4 = *reinterpret_cast<const float4*>(
                        Wc + (size_t)(g * 4 + j) * COUT + cow + cc * 4);
                    float a = av[j];
                    acc[cc * 4 + 0] = fmaf(a, w4.x, acc[cc * 4 + 0]);
                    acc[cc * 4 + 1] = fmaf(a, w4.y, acc[cc * 4 + 1]);
                    acc[cc * 4 + 2] = fmaf(a, w4.z, acc[cc * 4 + 2]);
                    acc[cc * 4 + 3] = fmaf(a, w4.w, acc[cc * 4 + 3]);
                }
            }
        }
        __syncthreads();
        zero(b);          // recycle buf b for chunk c+2
        __syncthreads();
    }

    const int n = bx * 64 + lane;
    if (n < NPTS) {
        float* po = partial + ((size_t)(ks % PSLOT) * NPTS + n) * COUT + cow;
        if constexpr (KSPLIT > PSLOT) {
            #pragma unroll
            for (int j = 0; j < C; ++j) atomicAdd(po + j, acc[j]);
        } else {
            #pragma unroll
            for (int cc = 0; cc < C / 4; ++cc)
                *reinterpret_cast<float4*>(po + cc * 4) =
                    make_float4(acc[cc * 4 + 0], acc[cc * 4 + 1],
                                acc[cc * 4 + 2], acc[cc * 4 + 3]);
        }
    }
}

// ---------------------------------------------------------------------------
// Kernel 4: combine K-split partials, normalize by neighbor count, bias, relu.
// ---------------------------------------------------------------------------
template<int COUT, int KSPLIT>
__global__ __launch_bounds__(256) void combine_kernel(
    const float* __restrict__ partial, const float* __restrict__ cnt,
    const float* __restrict__ bias, float* __restrict__ out) {
    int idx = blockIdx.x * 256 + threadIdx.x;
    if (idx >= NPTS * COUT) return;
    int n = idx / COUT, co = idx % COUT;
    float s = 0.f;
    #pragma unroll
    for (int k2 = 0; k2 < KSPLIT; ++k2)
        s += partial[((size_t)k2 * NPTS + n) * COUT + co];
    float c = cnt[n];
    if (c > 0.f) s /= fmaxf(c, 1.f);
    out[idx] = fmaxf(s + bias[co], 0.f);
}

// ---------------------------------------------------------------------------
// Kernel 5: fused FC chain. One wave per point, __shfl broadcasts.
// ---------------------------------------------------------------------------
__global__ __launch_bounds__(64) void fc_kernel(
    const float* __restrict__ x,
    const float* __restrict__ W1, const float* __restrict__ b1,
    const float* __restrict__ W2, const float* __restrict__ b2,
    const float* __restrict__ W3, const float* __restrict__ b3,
    const float* __restrict__ W4, const float* __restrict__ b4,
    float* __restrict__ out) {
    int n = blockIdx.x;
    int lane = threadIdx.x;
    float xv = (lane < 32) ? x[(size_t)n * 32 + lane] : 0.0f;

    float t = b1[lane];
    for (int ci = 0; ci < 32; ++ci)
        t = fmaf(__shfl(xv, ci), W1[ci * 64 + lane], t);
    float h1 = fmaxf(t, 0.0f);

    t = b2[lane];
    for (int ci = 0; ci < 64; ++ci)
        t = fmaf(__shfl(h1, ci), W2[ci * 64 + lane], t);
    float h2 = fmaxf(t, 0.0f);

    int l32 = lane & 31;
    t = b3[l32];
    for (int ci = 0; ci < 64; ++ci)
        t = fmaf(__shfl(h2, ci), W3[ci * 32 + l32], t);
    float h3 = fmaxf(t, 0.0f);

    int ch = (lane < 3) ? lane : 0;
    float o = b4[ch];
    for (int ci = 0; ci < 32; ++ci)
        o = fmaf(__shfl(h3, ci), W4[ci * 3 + ch], o);
    if (lane < 3) out[(size_t)n * 3 + lane] = o;
}

// ---------------------------------------------------------------------------
// launch
// ---------------------------------------------------------------------------
extern "C" void kernel_launch(void* const* d_in, const int* in_sizes, int n_in,
                              void* d_out, int out_size, void* d_ws, size_t ws_size,
                              hipStream_t stream) {
    const float* feats = (const float*)d_in[0];
    const float* pos   = (const float*)d_in[1];
    const int*   nidx  = (const int*)d_in[2];
    // d_in[3] (neighbor_mask) unused: mask recomputed exactly.
    const float* W1 = (const float*)d_in[4];
    const float* b1 = (const float*)d_in[5];
    const float* W2 = (const float*)d_in[6];
    const float* b2 = (const float*)d_in[7];
    const float* W3 = (const float*)d_in[8];
    const float* b3 = (const float*)d_in[9];
    const float* Wfc1 = (const float*)d_in[10];
    const float* bfc1 = (const float*)d_in[11];
    const float* Wfc2 = (const float*)d_in[12];
    const float* bfc2 = (const float*)d_in[13];
    const float* Wfc3 = (const float*)d_in[14];
    const float* bfc3 = (const float*)d_in[15];
    const float* Wout = (const float*)d_in[16];
    const float* bout = (const float*)d_in[17];

    char* ws = (char*)d_ws;
    uint2* contrib = (uint2*)(ws);                    // 20,578,304 B
    int*   starts  = (int*)  (ws + 20578304);         //    136,276 B
    float* cnt     = (float*)(ws + 20714624);         //     40,000 B
    float* x1      = (float*)(ws + 20754624);         //  2,560,000 B
    float* x2      = (float*)(ws + 23314624);         //  2,560,000 B
    float* x3      = (float*)(ws + 25874624);         //  1,280,000 B
    // geo (5.12 MB) dead after sort -> alias with partial region (10.24 MB)
    uint4* geo     = (uint4*)(ws + 27154624);
    float* partial = (float*)(ws + 27154624);

    const size_t PBYTES = (size_t)4 * NPTS * 64 * sizeof(float);  // 10.24 MB

    hipMemsetAsync(cnt, 0, NPTS * sizeof(float), stream);
    geom_kernel<<<(NPTS * KNB) / 256, 256, 0, stream>>>(pos, nidx, geo, cnt);
    sort_kernel<<<NSGT, 256, 0, stream>>>(geo, contrib, starts);

    // conv1: CIN=4, COUT=64, CPC=8 (KC=32), KSPLIT=8, PSLOT=4 (atomic)
    hipMemsetAsync(partial, 0, PBYTES, stream);
    conv_kernel<4, 64, 8, 8, 4><<<dim3(NSGT, 8), 512, 0, stream>>>(
        feats, W1, contrib, starts, partial);
    combine_kernel<64, 4><<<(NPTS * 64 + 255) / 256, 256, 0, stream>>>(
        partial, cnt, b1, x1);

    // conv2: CIN=64, COUT=64, CPC=1 (KC=64), KSPLIT=8, PSLOT=4 (atomic)
    hipMemsetAsync(partial, 0, PBYTES, stream);
    conv_kernel<64, 64, 1, 8, 4><<<dim3(NSGT, 8), 512, 0, stream>>>(
        x1, W2, contrib, starts, partial);
    combine_kernel<64, 4><<<(NPTS * 64 + 255) / 256, 256, 0, stream>>>(
        partial, cnt, b2, x2);

    // conv3: CIN=64, COUT=32, CPC=1, KSPLIT=8, PSLOT=8 (direct store)
    conv_kernel<64, 32, 1, 8, 8><<<dim3(NSGT, 8), 512, 0, stream>>>(
        x2, W3, contrib, starts, partial);
    combine_kernel<32, 8><<<(NPTS * 32 + 255) / 256, 256, 0, stream>>>(
        partial, cnt, b3, x3);

    fc_kernel<<<NPTS, 64, 0, stream>>>(x3, Wfc1, bfc1, Wfc2, bfc2,
                                       Wfc3, bfc3, Wout, bout, (float*)d_out);
}